// Round 4
// baseline (524.978 us; speedup 1.0000x reference)
//
#include <hip/hip_runtime.h>
#include <math.h>

#define N_OPS 320
#define CROWS 16                 // rows per chunk (4 chunks of 16 = 64 rows per block)
#define TPF (CROWS * 238)        // tile_prep floats per chunk = 3808
#define TPV (TPF / 4)            // float4s = 952
#define FANV (CROWS * 20)        // fan float4s per chunk = 320

__global__ __launch_bounds__(256) void mahjong_kernel(
    const float* __restrict__ meta,        // (N,6)
    const float* __restrict__ wall,        // (N,34,5)
    const float* __restrict__ tile_prep,   // (N,320,34,7)
    const float* __restrict__ fan_prep,    // (N,320,80)
    const float* __restrict__ redundant,   // (N,320,34)
    const float* __restrict__ W_throw,     // (11)
    const float* __restrict__ b_throw,     // (1)
    const float* __restrict__ fan_coeff,   // (80)
    const float* __restrict__ fan_mult,    // (80)
    const float* __restrict__ tile_coeff,  // (34)
    float* __restrict__ out_max,           // (N,5)
    float* __restrict__ out_weighted,      // (N,34)
    int n)
{
    const int blk  = blockIdx.x;
    const int b    = blk / 5;
    const int g    = blk % 5;
    const int tid  = threadIdx.x;
    const int wave = tid >> 6;
    const int lane = tid & 63;

    __shared__ __align__(16) float tp_sm[TPF];      // 15232 B, staged once per chunk
    __shared__ float terms_sm[CROWS * 34];          // 2176 B
    __shared__ float qp_sm[CROWS * 21];             // fan quad-partials, stride 21
    __shared__ float prob_sm[34];
    __shared__ float fc_sm[80];
    __shared__ float final_sm[CROWS];
    __shared__ float acc_sm[4][34];

    // ---- stage 0: prob_throw (Linear(11,1)) and fused fan coeff ----
    if (tid < 34) {
        float acc = b_throw[0];
        #pragma unroll
        for (int j = 0; j < 6; ++j) acc += meta[(size_t)b * 6 + j] * W_throw[j];
        const float* w = wall + ((size_t)b * 34 + tid) * 5;
        #pragma unroll
        for (int j = 0; j < 5; ++j) acc += w[j] * W_throw[6 + j];
        prob_sm[tid] = acc;
    }
    if (tid >= 64 && tid < 144) {
        int f = tid - 64;
        fc_sm[f] = fan_coeff[f] * fan_mult[f];
    }
    __syncthreads();

    float acc3 = 0.0f;       // stage-3 per-wave accumulator (lane < 34)
    float fsum_part = 0.0f;  // g==0: threads 0..15 accumulate final sums

    for (int c = 0; c < 4; ++c) {
        const size_t row0 = (size_t)b * N_OPS + g * 64 + c * CROWS;

        if (c) __syncthreads();  // protect LDS reuse across chunks

        // ---- phase A: coalesced float4 staging (every cache line touched once) ----
        {
            const float4* tsrc = (const float4*)(tile_prep + row0 * 238);
            float4* tdst = (float4*)tp_sm;
            #pragma unroll
            for (int k = 0; k < 4; ++k) {
                const int i = tid + 256 * k;
                if (i < TPV) tdst[i] = tsrc[i];
            }
            const float4* fsrc = (const float4*)(fan_prep + row0 * 80);
            #pragma unroll
            for (int k = 0; k < 2; ++k) {
                const int i = tid + 256 * k;
                if (i < FANV) {
                    float4 v = fsrc[i];
                    const int r = i / 20;
                    const int q = i - r * 20;
                    const int f = 4 * q;
                    qp_sm[r * 21 + q] = v.x * fc_sm[f]     + v.y * fc_sm[f + 1]
                                      + v.z * fc_sm[f + 2] + v.w * fc_sm[f + 3];
                }
            }
        }
        __syncthreads();

        // ---- phase B: per-(row,tile) terms from LDS (stride-7 reads: conflict-free) ----
        #pragma unroll
        for (int k = 0; k < 3; ++k) {
            const int tau = tid + 256 * k;
            if (tau < CROWS * 34) {
                const int r = tau / 34;
                const int t = tau - r * 34;
                const float* e = tp_sm + 7 * tau;
                float c0 = e[0], c1 = e[1], c2 = e[2], c3 = e[3];
                float c4 = e[4], c5 = e[5], c6 = e[6];
                // prob>0 by construction; tile_hidden_ct in [0.5,1.5] -> no inf/nan
                terms_sm[tau] = c0 * exp2f(c1 * log2f(prob_sm[t])) + c6
                              + (c3 * c2 / c4) * c5;
            }
        }
        __syncthreads();

        // ---- phase C: finalize final_prob_throw per row ----
        if (tid < CROWS) {
            const float* tr = terms_sm + tid * 34;
            float p = 1.0f;
            #pragma unroll
            for (int t = 0; t < 34; ++t) p *= tr[t];
            const float* qr = qp_sm + tid * 21;
            float q = 0.0f;
            #pragma unroll
            for (int j = 0; j < 20; ++j) q += qr[j];
            float fin = p * 100.0f * q;
            final_sm[tid] = fin;
            fsum_part += fin;
        }
        __syncthreads();

        // ---- phase D: tile_bound_winrate partials (4 rows per wave) ----
        if (lane < 34) {
            const float* rr0 = redundant + (row0 + wave * 4) * 34;
            #pragma unroll
            for (int i = 0; i < 4; ++i)
                acc3 += rr0[i * 34 + lane] * final_sm[wave * 4 + i];
        }
    }

    if (lane < 34) acc_sm[wave][lane] = acc3;
    __syncthreads();

    // ---- outputs (wave 0 only) ----
    if (wave == 0) {
        float tbw = 0.0f;
        if (lane < 34)
            tbw = acc_sm[0][lane] + acc_sm[1][lane] + acc_sm[2][lane] + acc_sm[3][lane];
        if (g == 0) {
            if (lane < 34)
                out_weighted[(size_t)b * 34 + lane] = tbw * tile_coeff[lane];
            float fs = fsum_part;  // lanes 0..15 hold partials; others 0
            #pragma unroll
            for (int sh = 1; sh < 64; sh <<= 1) fs += __shfl_xor(fs, sh);
            if (lane == 0) out_max[(size_t)b * 5] = fs;
        } else {
            float m = (lane < 34) ? tbw : -INFINITY;
            #pragma unroll
            for (int sh = 1; sh < 64; sh <<= 1) m = fmaxf(m, __shfl_xor(m, sh));
            if (lane == 0) out_max[(size_t)b * 5 + g] = m;
        }
    }
}

extern "C" void kernel_launch(void* const* d_in, const int* in_sizes, int n_in,
                              void* d_out, int out_size, void* d_ws, size_t ws_size,
                              hipStream_t stream) {
    const float* meta       = (const float*)d_in[0];
    const float* wall       = (const float*)d_in[1];
    const float* tile_prep  = (const float*)d_in[2];
    const float* fan_prep   = (const float*)d_in[3];
    const float* redundant  = (const float*)d_in[4];
    // d_in[5] count_prep, d_in[6] chi_peng_count_remain: unused by reference
    const float* W_throw    = (const float*)d_in[7];
    const float* b_throw    = (const float*)d_in[8];
    const float* fan_coeff  = (const float*)d_in[9];
    const float* fan_mult   = (const float*)d_in[10];
    const float* tile_coeff = (const float*)d_in[11];

    int n = in_sizes[0] / 6;
    float* out_max      = (float*)d_out;            // (n,5)
    float* out_weighted = out_max + (size_t)n * 5;  // (n,34)

    dim3 grid(n * 5), block(256);
    hipLaunchKernelGGL(mahjong_kernel, grid, block, 0, stream,
                       meta, wall, tile_prep, fan_prep, redundant,
                       W_throw, b_throw, fan_coeff, fan_mult, tile_coeff,
                       out_max, out_weighted, n);
}